// Round 3
// baseline (748.587 us; speedup 1.0000x reference)
//
#include <hip/hip_runtime.h>
#include <hip/hip_fp16.h>

// Problem constants
#define Bc  64
#define Sc  256
#define Icc 256
#define Hh  512
#define HW  1024   // 2*Hh

using v2f = __attribute__((ext_vector_type(2))) float;

__device__ __forceinline__ float fast_tanh(float x) {
  float e = __expf(2.0f * x);
  return 1.0f - 2.0f * __builtin_amdgcn_rcpf(e + 1.0f);
}

template <int P>
__device__ __forceinline__ float swzf(float x) {
  return __int_as_float(__builtin_amdgcn_ds_swizzle(__float_as_int(x), P));
}
template <int P>
__device__ __forceinline__ v2f swzadd2(v2f x) {  // x + swizzle_xor(x)
  v2f r;
  r.x = x.x + swzf<P>(x.x);
  r.y = x.y + swzf<P>(x.y);
  return r;
}
template <int C>
__device__ __forceinline__ float dppaddf(float x) {  // x + dpp_quadperm(x)
  return x + __int_as_float(
                 __builtin_amdgcn_mov_dpp(__float_as_int(x), C, 0xf, 0xf, true));
}
template <int C>
__device__ __forceinline__ v2f dppadd2(v2f x) {
  v2f r;
  r.x = dppaddf<C>(x.x);
  r.y = dppaddf<C>(x.y);
  return r;
}

template <typename T>
__device__ __forceinline__ float ldf(const T* p) {
  if constexpr (sizeof(T) == 4) return *p;
  else return __half2float(*p);
}
template <typename T>
__device__ __forceinline__ void stf(T* p, float v) {
  if constexpr (sizeof(T) == 4) *p = v;
  else *p = __float2half(v);
}

// ---------------- GEMM: I[m][h] = sum_k X[m][k] * W[h][k] ----------------
// M=16384, N=1024, K=256. 128x64 tile, 256 threads, 8x4 per thread.
template <typename T>
__global__ __launch_bounds__(256, 4) void gemm_xw(const float* __restrict__ X,
                                                  const float* __restrict__ Wm,
                                                  T* __restrict__ Out) {
  __shared__ float As[16][132];  // [k][m], pad 4
  __shared__ float Bs[16][68];   // [k][n], pad 4
  const int tid = threadIdx.x;
  const int m0 = blockIdx.x << 7;
  const int n0 = blockIdx.y << 6;
  const int tx4 = (tid & 15) << 2;
  const int ty4 = (tid >> 4) << 2;
  const int lr = tid >> 2;
  const int lk = (tid & 3) << 2;

  float acc[8][4];
#pragma unroll
  for (int i = 0; i < 8; ++i)
#pragma unroll
    for (int j = 0; j < 4; ++j) acc[i][j] = 0.0f;

  const float* xg0 = X + (size_t)(m0 + lr) * Icc + lk;
  const float* xg1 = X + (size_t)(m0 + 64 + lr) * Icc + lk;
  const float* wg  = Wm + (size_t)(n0 + lr) * Icc + lk;

  for (int k0 = 0; k0 < Icc; k0 += 16) {
    float4 a0 = *(const float4*)(xg0 + k0);
    float4 a1 = *(const float4*)(xg1 + k0);
    float4 bv = *(const float4*)(wg + k0);
    __syncthreads();
    As[lk + 0][lr] = a0.x; As[lk + 1][lr] = a0.y;
    As[lk + 2][lr] = a0.z; As[lk + 3][lr] = a0.w;
    As[lk + 0][lr + 64] = a1.x; As[lk + 1][lr + 64] = a1.y;
    As[lk + 2][lr + 64] = a1.z; As[lk + 3][lr + 64] = a1.w;
    Bs[lk + 0][lr] = bv.x; Bs[lk + 1][lr] = bv.y;
    Bs[lk + 2][lr] = bv.z; Bs[lk + 3][lr] = bv.w;
    __syncthreads();
#pragma unroll
    for (int kk = 0; kk < 16; ++kk) {
      float a[8], bq[4];
      *(float4*)&a[0] = *(const float4*)&As[kk][ty4];
      *(float4*)&a[4] = *(const float4*)&As[kk][ty4 + 64];
      *(float4*)&bq[0] = *(const float4*)&Bs[kk][tx4];
#pragma unroll
      for (int i = 0; i < 8; ++i)
#pragma unroll
        for (int j = 0; j < 4; ++j) acc[i][j] = fmaf(a[i], bq[j], acc[i][j]);
    }
  }
#pragma unroll
  for (int i = 0; i < 8; ++i) {
    const int mrow = m0 + ((i < 4) ? (ty4 + i) : (64 + ty4 + i - 4));
    T* op = Out + (size_t)mrow * HW + n0 + tx4;
    if constexpr (sizeof(T) == 4) {
      *(float4*)op = make_float4(acc[i][0], acc[i][1], acc[i][2], acc[i][3]);
    } else {
#pragma unroll
      for (int j = 0; j < 4; ++j) stf(op + j, acc[i][j]);
    }
  }
}

// ---------------- Scan ----------------
// Grid (16,64): blockIdx.y = batch, blockIdx.x = row-block (32 rows).
// 256 threads: cc = tid&31 (16-col chunk), rg = tid>>5 (4-row group).
// Thread state: m2[4][8] (4 rows x 16 cols, packed float2, 64 VGPRs),
// kt_own[8] (kt for its 16 cols), vs/vt for 4 rows (replicated over cc).
// One barrier per step; ikv reduction is intra-wave DPP + ds_swizzle.
template <typename T>
__global__ __launch_bounds__(256, 4) void scan_kernel(const T* __restrict__ If,
                                                      float* __restrict__ mem_out,
                                                      float* __restrict__ keys,
                                                      float* __restrict__ vals) {
  const int b = blockIdx.y;
  const int rb = blockIdx.x;
  const int tid = threadIdx.x;
  const int cc = tid & 31;
  const int rg = tid >> 5;
  const int r0 = rb << 5;

  // k_s: 512 floats with +4 pad per 32 (stride 36) -> b128 reads <=2-way
  __shared__ __align__(16) float k_s[2][576];

  constexpr float ALPHA = 0.90483741803595957f;  // exp(-1/10)
  constexpr float DT    = 0.95122942450071400f;  // exp(-1/20)
  constexpr float OMD   = 0.04877057549928599f;  // 1 - DT
  constexpr float LR_   = 0.01f;

  v2f m2[4][8];
#pragma unroll
  for (int i = 0; i < 4; ++i)
#pragma unroll
    for (int j = 0; j < 8; ++j) m2[i][j] = (v2f){0.f, 0.f};
  v2f kt_own[8];
#pragma unroll
  for (int j = 0; j < 8; ++j) kt_own[j] = (v2f){0.f, 0.f};
  v2f vs01 = {0.f, 0.f}, vs23 = {0.f, 0.f};
  v2f vt01 = {0.f, 0.f}, vt23 = {0.f, 0.f};
  float ks0 = 0.f, ks1 = 0.f;

  const T* ibase = If + (size_t)b * Sc * HW;
  float* keysb = keys + (size_t)b * Sc * Hh;
  float* valsb = vals + (size_t)b * Sc * Hh;

  const int h0 = 2 * tid;                       // this thread's two k-chains
  const int sw0 = h0 + ((h0 >> 5) << 2);        // swizzled store offset
  const int kbase = (cc << 4) + ((cc >> 1) << 2);  // phys offset of col cc*16

  for (int t = 0; t < Sc; ++t) {
    const T* row = ibase + (size_t)t * HW;
    const int buf = t & 1;

    // ---- phase 1: k-channel recurrence (2 chains/thread) ----
    float ik0, ik1;
    v2f iv01, iv23;
    if constexpr (sizeof(T) == 4) {
      float2 v2 = *(const float2*)(row + h0);
      ik0 = v2.x; ik1 = v2.y;
      float4 iv4 = *(const float4*)(row + 512 + r0 + (rg << 2));
      iv01.x = iv4.x; iv01.y = iv4.y; iv23.x = iv4.z; iv23.y = iv4.w;
    } else {
      float2 v2 = __half22float2(*(const __half2*)(row + h0));
      ik0 = v2.x; ik1 = v2.y;
      float2 a2 = __half22float2(*(const __half2*)(row + 512 + r0 + (rg << 2)));
      float2 b2 = __half22float2(*(const __half2*)(row + 514 + r0 + (rg << 2)));
      iv01.x = a2.x; iv01.y = a2.y; iv23.x = b2.x; iv23.y = b2.y;
    }
    ks0 = ALPHA * ks0 + ik0;
    ks1 = ALPHA * ks1 + ik1;
    float k0 = fast_tanh(ks0);
    float k1 = fast_tanh(ks1);
    *(float2*)&k_s[buf][sw0] = make_float2(k0, k1);
    if (rb == 0) {
      *(float2*)&keysb[t * Hh + h0] = make_float2(k0, k1);
    }
    __syncthreads();  // the ONLY barrier per step

    // ---- phase 2: matvec partials (old mem, new k) + kt register update ----
    const float4* kc = (const float4*)&k_s[buf][kbase];
    v2f acc0 = {0.f, 0.f}, acc1 = {0.f, 0.f}, acc2 = {0.f, 0.f}, acc3 = {0.f, 0.f};
#pragma unroll
    for (int q = 0; q < 4; ++q) {
      float4 kq = kc[q];
      v2f ka; ka.x = kq.x; ka.y = kq.y;
      v2f kb; kb.x = kq.z; kb.y = kq.w;
      const int j = q << 1;
      acc0 += m2[0][j] * ka; acc0 += m2[0][j + 1] * kb;
      acc1 += m2[1][j] * ka; acc1 += m2[1][j + 1] * kb;
      acc2 += m2[2][j] * ka; acc2 += m2[2][j + 1] * kb;
      acc3 += m2[3][j] * ka; acc3 += m2[3][j + 1] * kb;
      kt_own[j]     = DT * kt_own[j]     + OMD * ka;
      kt_own[j + 1] = DT * kt_own[j + 1] + OMD * kb;
    }
    v2f p01, p23;
    p01.x = acc0.x + acc0.y; p01.y = acc1.x + acc1.y;
    p23.x = acc2.x + acc2.y; p23.y = acc3.x + acc3.y;
    // reduce over the 32 cc lanes (xor1/2 via DPP quad_perm, 4/8/16 via swizzle)
    p01 = dppadd2<0xB1>(p01); p23 = dppadd2<0xB1>(p23);
    p01 = dppadd2<0x4E>(p01); p23 = dppadd2<0x4E>(p23);
    p01 = swzadd2<0x101F>(p01); p23 = swzadd2<0x101F>(p23);
    p01 = swzadd2<0x201F>(p01); p23 = swzadd2<0x201F>(p23);
    p01 = swzadd2<0x401F>(p01); p23 = swzadd2<0x401F>(p23);

    // ---- phase 3: v-recurrence for the 4 rows, replicated across cc ----
    vs01 = ALPHA * vs01 + iv01 + 0.2f * p01;
    vs23 = ALPHA * vs23 + iv23 + 0.2f * p23;
    v2f v01, v23;
    v01.x = fast_tanh(vs01.x); v01.y = fast_tanh(vs01.y);
    v23.x = fast_tanh(vs23.x); v23.y = fast_tanh(vs23.y);
    vt01 = DT * vt01 + OMD * v01;
    vt23 = DT * vt23 + OMD * v23;
    v2f a01 = 1.0f - LR_ * vt01 * vt01;
    v2f a23 = 1.0f - LR_ * vt23 * vt23;
    v2f c01 = LR_ * vt01;
    v2f c23 = LR_ * vt23;
    if (cc == 0) {
      *(float4*)&valsb[t * Hh + r0 + (rg << 2)] =
          make_float4(v01.x, v01.y, v23.x, v23.y);
    }

    // ---- phase 4: rank-1 mem update (new kt from registers, no LDS) ----
    const float a0 = a01.x, a1 = a01.y, a2v = a23.x, a3 = a23.y;
    const float c0 = c01.x, c1 = c01.y, c2v = c23.x, c3 = c23.y;
#pragma unroll
    for (int j = 0; j < 8; ++j) {
      v2f kv = kt_own[j];
      m2[0][j] = m2[0][j] * a0  + c0  * kv;
      m2[1][j] = m2[1][j] * a1  + c1  * kv;
      m2[2][j] = m2[2][j] * a2v + c2v * kv;
      m2[3][j] = m2[3][j] * a3  + c3  * kv;
    }
  }

  // epilogue: write mem
#pragma unroll
  for (int i = 0; i < 4; ++i) {
    float* mb = mem_out + (size_t)b * Hh * Hh +
                (size_t)(r0 + (rg << 2) + i) * Hh + (cc << 4);
#pragma unroll
    for (int q = 0; q < 4; ++q) {
      *(float4*)(mb + 4 * q) = make_float4(m2[i][2 * q].x, m2[i][2 * q].y,
                                           m2[i][2 * q + 1].x, m2[i][2 * q + 1].y);
    }
  }
}

extern "C" void kernel_launch(void* const* d_in, const int* in_sizes, int n_in,
                              void* d_out, int out_size, void* d_ws, size_t ws_size,
                              hipStream_t stream) {
  const float* x = (const float*)d_in[0];   // (64,256,256) fp32
  const float* W = (const float*)d_in[1];   // (1024,256) fp32
  float* out = (float*)d_out;
  float* mem_out = out;                          // 16,777,216 floats
  float* keys    = out + 16777216;               //  8,388,608 floats
  float* vals    = out + 25165824;               //  8,388,608 floats

  const dim3 gemm_grid(128, 16), gemm_blk(256);
  const dim3 scan_grid(16, 64),  scan_blk(256);
  const size_t i_elems = (size_t)Bc * Sc * HW;   // 16,777,216

  if (ws_size >= i_elems * sizeof(float)) {
    float* If = (float*)d_ws;
    gemm_xw<float><<<gemm_grid, gemm_blk, 0, stream>>>(x, W, If);
    scan_kernel<float><<<scan_grid, scan_blk, 0, stream>>>(If, mem_out, keys, vals);
  } else {
    __half* If = (__half*)d_ws;
    gemm_xw<__half><<<gemm_grid, gemm_blk, 0, stream>>>(x, W, If);
    scan_kernel<__half><<<scan_grid, scan_blk, 0, stream>>>(If, mem_out, keys, vals);
  }
}